// Round 3
// baseline (205.929 us; speedup 1.0000x reference)
//
#include <hip/hip_runtime.h>
#include <hip/hip_fp16.h>

#define EPSF 1e-6f

typedef _Float16 f16x8 __attribute__((ext_vector_type(8)));
typedef float f32x4 __attribute__((ext_vector_type(4)));

#define BK 32                  // K-tile (halves); LDS row = 64 B (4 x 16B segs)
#define SMEM_BYTES 49152       // fg scratch dominates: 4 waves x 48x64 f32
#define BUF_BYTES 10240        // A staging: 160 rows x 64 B

#define AS1 __attribute__((address_space(1)))
#define AS3 __attribute__((address_space(3)))

#define VM_WAIT(N) asm volatile("s_waitcnt vmcnt(" #N ")" ::: "memory")
#define LGKM0()    asm volatile("s_waitcnt lgkmcnt(0)" ::: "memory")

// ---------- wave sum -> scalar (SGPR) : pure DPP + readlane, no DS ops ----------
template <int CTRL>
__device__ __forceinline__ float dpp_add(float x) {
    int y = __builtin_amdgcn_update_dpp(0, __float_as_int(x), CTRL, 0xf, 0xf, true);
    return x + __int_as_float(y);
}

__device__ __forceinline__ float wave_sum_bc(float x) {
    x = dpp_add<0xB1>(x);   // quad_perm xor1
    x = dpp_add<0x4E>(x);   // quad_perm xor2
    x = dpp_add<0x141>(x);  // row_half_mirror (xor4)
    x = dpp_add<0x140>(x);  // row_mirror (xor8) -> 16-group sums
    x = dpp_add<0x142>(x);  // row_bcast15
    x = dpp_add<0x143>(x);  // row_bcast31
    return __int_as_float(__builtin_amdgcn_readlane(__float_as_int(x), 63));
}

// ---------------- Phase 1: prepend cls, +EPS, L2-normalize, store fp16 packed ----------------
// A: [64 groups][80 rows][1024]  rows 0..36 = img 2g, 37..73 = img 2g+1, 74..79 = 0
// B: [128 caps][64 rows][1024]   row 0 = cls, 1..50 = caps, 51..63 = 0
__global__ __launch_bounds__(256) void norm_kernel(
        const float* __restrict__ img_cls, const float* __restrict__ imgs,
        const float* __restrict__ cap_cls, const float* __restrict__ caps,
        __half* __restrict__ Ah, __half* __restrict__ Bh) {
    __shared__ float red[4];
    const int row = blockIdx.x;
    const int tid = threadIdx.x;

    const float* src = nullptr;
    __half* dst;
    float eps_add = EPSF;
    if (row < 64 * 80) {
        const int g = row / 80, r = row % 80;
        dst = Ah + (size_t)row * 1024;
        int i = -1, rr = 0;
        if (r < 37)      { i = 2 * g;     rr = r; }
        else if (r < 74) { i = 2 * g + 1; rr = r - 37; }
        if (i >= 0) {
            if (rr == 0) { src = img_cls + (size_t)i * 1024; eps_add = 0.0f; }
            else         { src = imgs + ((size_t)i * 36 + (rr - 1)) * 1024; }
        }
    } else {
        const int row2 = row - 64 * 80;
        const int t = row2 >> 6, r = row2 & 63;
        dst = Bh + (size_t)row2 * 1024;
        if (r == 0)       { src = cap_cls + (size_t)t * 1024; eps_add = 0.0f; }
        else if (r <= 50) { src = caps + ((size_t)t * 50 + (r - 1)) * 1024; }
    }

    if (src == nullptr) {  // pad row: zeros (uniform across block)
        ushort4 z; z.x = z.y = z.z = z.w = 0;
        reinterpret_cast<ushort4*>(dst)[tid] = z;
        return;
    }

    float4 v = reinterpret_cast<const float4*>(src)[tid];
    v.x += eps_add; v.y += eps_add; v.z += eps_add; v.w += eps_add;
    float ss = v.x * v.x + v.y * v.y + v.z * v.z + v.w * v.w;
    #pragma unroll
    for (int m = 1; m <= 32; m <<= 1) ss += __shfl_xor(ss, m);
    if ((tid & 63) == 0) red[tid >> 6] = ss;
    __syncthreads();
    const float tot = red[0] + red[1] + red[2] + red[3];
    const float rn = 1.0f / sqrtf(tot);

    ushort4 o;
    o.x = __half_as_ushort(__float2half(v.x * rn));
    o.y = __half_as_ushort(__float2half(v.y * rn));
    o.z = __half_as_ushort(__float2half(v.z * rn));
    o.w = __half_as_ushort(__float2half(v.w * rn));
    reinterpret_cast<ushort4*>(dst)[tid] = o;
}

// ---------------- Phase 2: fused GEMM + Sinkhorn ----------------
// Block: 160 A rows x 128 B cols, 4 waves; wave (wm,wn) computes 80x64.
// A staged in LDS (2x reuse across wn pair), conflict-free XOR swizzle.
// B loaded DIRECT global->VGPR (exact MFMA frag layout in Bh), register
// double-buffered one tile ahead.  vmcnt FIFO/tile: [B(kt+1)=4, A(kt+2)=a],
// a = 3 (waves 0,1) / 2 (waves 2,3).
__device__ __forceinline__ void stage_octA(const __half* __restrict__ Ag,
                                           __half* buf, int kb, int o, size_t lofs) {
    const __half* src = Ag + (size_t)o * 16384 + kb + lofs;
    __builtin_amdgcn_global_load_lds((const AS1 void*)src,
                                     (AS3 void*)(buf + o * 512), 16, 0, 0);
}

__device__ __forceinline__ void stage_A(const __half* __restrict__ Ag,
                                        __half* buf, int kb, int wave, size_t lofs) {
    stage_octA(Ag, buf, kb, wave, lofs);
    stage_octA(Ag, buf, kb, wave + 4, lofs);
    if (wave < 2) stage_octA(Ag, buf, kb, wave + 8, lofs);
}

__device__ __forceinline__ void ds_af(const __half* buf, int wm, int fr, int q4,
                                      f16x8 af[5]) {
    const int soff = ((q4 ^ ((fr >> 1) & 3)) * 8);   // swizzled seg, halves
    #pragma unroll
    for (int m = 0; m < 5; ++m) {
        const int R = wm * 80 + m * 16 + fr;
        af[m] = *reinterpret_cast<const f16x8*>(buf + R * BK + soff);
    }
}

__device__ __forceinline__ void load_bf(const __half* __restrict__ Bg, int kt,
                                        int wn, int fr, int q4, f16x8 bf[4]) {
    const __half* p = Bg + (size_t)(wn * 64 + fr) * 1024 + q4 * 8 + kt * BK;
    #pragma unroll
    for (int n = 0; n < 4; ++n)
        bf[n] = *reinterpret_cast<const f16x8*>(p + (size_t)n * 16 * 1024);
}

__device__ __forceinline__ void mfma_cluster(f32x4 acc[5][4], const f16x8 af[5],
                                             const f16x8 bf[4]) {
    __builtin_amdgcn_s_setprio(1);
    #pragma unroll
    for (int m = 0; m < 5; ++m)
        #pragma unroll
        for (int n = 0; n < 4; ++n)
            acc[m][n] = __builtin_amdgcn_mfma_f32_16x16x32_f16(af[m], bf[n], acc[m][n], 0, 0, 0);
    __builtin_amdgcn_s_setprio(0);
}

__global__ __launch_bounds__(256, 3) void fused_kernel(
        const __half* __restrict__ Ah, const __half* __restrict__ Bh,
        const int* __restrict__ img_lens, const int* __restrict__ cap_lens,
        float* __restrict__ out) {
    __shared__ __align__(16) char smem[SMEM_BYTES];   // 49,152 B -> 3 blocks/CU
    __half* lds0 = reinterpret_cast<__half*>(smem);
    __half* lds1 = reinterpret_cast<__half*>(smem + BUF_BYTES);

    // XCD-chunked mapping: 8 consecutive blocks share bx across 8 by slices.
    const int idx = blockIdx.x;            // 0..2047
    const int xcd = idx & 7;
    const int within = idx >> 3;           // 0..255
    const int bx = within >> 3;            // 0..31  (A double-group)
    const int by = xcd * 8 + (within & 7); // 0..63  (cap pair)

    const int tid = threadIdx.x;
    const int wave = tid >> 6;
    const int lane = tid & 63;
    const int wm = wave >> 1, wn = wave & 1;
    const int fr = lane & 15;
    const int q4 = lane >> 4;

    const __half* Ag = Ah + (size_t)bx * 160 * 1024;
    const __half* Bg = Bh + (size_t)by * 2 * 64 * 1024;

    // staging source offset: rsub = lane>>2 (row in hexadecet); stored slot
    // (lane&3) holds global seg (lane&3) ^ ((lane>>3)&3).  LDS dest linear.
    const int rsub = lane >> 2;
    const int segsrc = (lane & 3) ^ ((lane >> 3) & 3);
    const size_t lofs = (size_t)rsub * 1024 + (size_t)(segsrc * 8);

    f32x4 acc[5][4];
    #pragma unroll
    for (int m = 0; m < 5; ++m)
        #pragma unroll
        for (int n = 0; n < 4; ++n) {
            f32x4 z = {0.0f, 0.0f, 0.0f, 0.0f};
            acc[m][n] = z;
        }

    f16x8 bfA[4], bfB[4];

    // Prologue: B(0) -> bfA; A(0), A(1) staged.  FIFO: [B0=4, A0=a, A1=a]
    load_bf(Bg, 0, wn, fr, q4, bfA);
    stage_A(Ag, lds0, 0, wave, lofs);
    stage_A(Ag, lds1, BK, wave, lofs);
    if (wave < 2) { VM_WAIT(3); } else { VM_WAIT(2); }   // B0 + A0 landed
    __builtin_amdgcn_s_barrier();

    // Per tile kt:
    //   ds af(A[kt&1]); vmcnt(a) [bf_cur=B(kt) ready]; issue B(kt+1)->bf_nxt;
    //   MFMA(af, bf_cur); lgkm0+bar [A reads retired -> overwrite safe];
    //   stage A(kt+2) -> A[kt&1]; vmcnt(4+a) [A(kt+1) landed]; bar
    #define GEMM_TILE(KT, LDSBUF, CUR, NXT)                               \
    {                                                                     \
        f16x8 af[5];                                                      \
        ds_af((LDSBUF), wm, fr, q4, af);                                  \
        if (wave < 2) { VM_WAIT(3); } else { VM_WAIT(2); }                \
        load_bf(Bg, (KT) + 1, wn, fr, q4, (NXT));                         \
        mfma_cluster(acc, af, (CUR));                                     \
        LGKM0();                                                          \
        __builtin_amdgcn_s_barrier();                                     \
        stage_A(Ag, (LDSBUF), ((KT) + 2) * BK, wave, lofs);               \
        if (wave < 2) { VM_WAIT(7); } else { VM_WAIT(6); }                \
        __builtin_amdgcn_s_barrier();                                     \
    }

    #pragma unroll 1
    for (int kt = 0; kt < 30; kt += 2) {
        GEMM_TILE(kt, lds0, bfA, bfB);
        GEMM_TILE(kt + 1, lds1, bfB, bfA);
    }
    #undef GEMM_TILE

    // ---- tile 30 (no A staging; A(31) in flight) ----
    {
        f16x8 af[5];
        ds_af(lds0, wm, fr, q4, af);
        if (wave < 2) { VM_WAIT(3); } else { VM_WAIT(2); }   // B(30) ready
        load_bf(Bg, 31, wn, fr, q4, bfB);
        mfma_cluster(acc, af, bfA);
        LGKM0();
        VM_WAIT(4);                       // A(31) landed (B31 stays in flight)
        __builtin_amdgcn_s_barrier();
    }
    // ---- tile 31 ----
    {
        f16x8 af[5];
        ds_af(lds1, wm, fr, q4, af);
        VM_WAIT(0);                       // B(31) ready
        mfma_cluster(acc, af, bfB);
    }

    __syncthreads();   // staging buffers become per-wave fg scratch

    // ---------------- Sinkhorn: wave-private fg region (48x64 XOR-swizzled), 2 passes ----------------
    float* fg = reinterpret_cast<float*>(smem) + wave * (48 * 64);
    const int orow = q4 * 4;

    #pragma unroll
    for (int p = 0; p < 2; ++p) {
        if (p) {  // wave-local WAR: pass-0 fg reads must retire before rewrite
            LGKM0();
        }
        #pragma unroll
        for (int pm = 0; pm < 3; ++pm) {
            #pragma unroll
            for (int n = 0; n < 4; ++n) {
                const int colbase = (n * 16 + fr) ^ (q4 << 4);   // (row>>2)&3 == q4
                #pragma unroll
                for (int q = 0; q < 4; ++q)
                    fg[(pm * 16 + orow + q) * 64 + colbase] = acc[pm + 2 * p][n][q];
            }
        }

        const int i = 4 * bx + 2 * wm + p;
        const int t = 2 * by + wn;
        const int il = img_lens[i] + 1;        // 2..37
        const int cl = cap_lens[t] + 1;        // 2..51
        const bool vcol = lane < cl;
        const int rbase = p ? 5 : 0;           // pass-1 rows 37..73 = local 5..41

        #define FGR(r_) fg[((r_) + rbase) * 64 + \
                           (lane ^ (((((r_) + rbase) >> 2) & 3) << 4))]

        float P[37];
        float ts[4] = {0.f, 0.f, 0.f, 0.f};
        #pragma unroll
        for (int r = 0; r < 37; ++r) {
            if (r < il) {                       // wave-uniform branch
                const float f = FGR(r);
                const float pe = vcol ? __expf((f - 1.0f) * 10.0f) : 0.0f;
                P[r] = pe;
                ts[r & 3] += pe;
            } else {
                P[r] = 0.0f;
            }
        }
        float tot = (ts[0] + ts[1]) + (ts[2] + ts[3]);
        tot = wave_sum_bc(tot);
        const float s0 = __builtin_amdgcn_rcpf(tot + EPSF);
        #pragma unroll
        for (int r = 0; r < 37; ++r) P[r] *= s0;

        const float rmarg = 1.0f / (float)il;
        const float cmarg = 1.0f / (float)cl;
        for (int it = 0; it < 3; ++it) {
            #pragma unroll
            for (int r = 0; r < 37; ++r) {
                if (r < il) {
                    const float u = wave_sum_bc(P[r]);
                    P[r] *= rmarg * __builtin_amdgcn_rcpf(u + EPSF);
                }
            }
            float vs[4] = {EPSF, 0.f, 0.f, 0.f};
            #pragma unroll
            for (int r = 0; r < 37; ++r) vs[r & 3] += P[r];
            const float v = (vs[0] + vs[1]) + (vs[2] + vs[3]);
            const float cs = vcol ? cmarg * __builtin_amdgcn_rcpf(v) : 0.0f;
            #pragma unroll
            for (int r = 0; r < 37; ++r) P[r] *= cs;
        }

        float ls[4] = {0.f, 0.f, 0.f, 0.f};
        #pragma unroll
        for (int r = 0; r < 37; ++r) {
            if (r < il) ls[r & 3] += FGR(r) * P[r];   // re-read fg
        }
        float local = (ls[0] + ls[1]) + (ls[2] + ls[3]);
        local = wave_sum_bc(local);
        if (lane == 0) out[i * 128 + t] = local;
        #undef FGR
    }
}

extern "C" void kernel_launch(void* const* d_in, const int* in_sizes, int n_in,
                              void* d_out, int out_size, void* d_ws, size_t ws_size,
                              hipStream_t stream) {
    const float* img_cls  = (const float*)d_in[0];
    const float* imgs     = (const float*)d_in[1];
    const float* cap_cls  = (const float*)d_in[2];
    const float* caps     = (const float*)d_in[3];
    const int*   img_lens = (const int*)d_in[4];
    const int*   cap_lens = (const int*)d_in[5];
    float* out = (float*)d_out;

    __half* Ah = (__half*)d_ws;                          // 64*80*1024 halves = 10.5 MB
    __half* Bh = Ah + (size_t)64 * 80 * 1024;            // 128*64*1024 halves = 16.8 MB

    norm_kernel<<<64 * 80 + 128 * 64, 256, 0, stream>>>(img_cls, imgs, cap_cls, caps, Ah, Bh);
    fused_kernel<<<2048, 256, 0, stream>>>(Ah, Bh, img_lens, cap_lens, out);
}

// Round 4
// 168.224 us; speedup vs baseline: 1.2241x; 1.2241x over previous
//
#include <hip/hip_runtime.h>
#include <hip/hip_fp16.h>

#define EPSF 1e-6f

typedef _Float16 f16x8 __attribute__((ext_vector_type(8)));
typedef float f32x4 __attribute__((ext_vector_type(4)));

#define BK 32                  // K-tile (halves); LDS row = 64 B (4 x 16B segs)
#define SMEM_BYTES 37888       // max(2 x 18432 staging, 4 x 9472 fg scratch)
#define BUF_BYTES 18432        // 288 rows x 64 B

#define AS1 __attribute__((address_space(1)))
#define AS3 __attribute__((address_space(3)))

#define VM_WAIT(N) asm volatile("s_waitcnt vmcnt(" #N ")" ::: "memory")
#define LGKM0()    asm volatile("s_waitcnt lgkmcnt(0)" ::: "memory")

// ---------- wave sum -> scalar (SGPR) : pure DPP + readlane, no DS ops ----------
template <int CTRL>
__device__ __forceinline__ float dpp_add(float x) {
    int y = __builtin_amdgcn_update_dpp(0, __float_as_int(x), CTRL, 0xf, 0xf, true);
    return x + __int_as_float(y);
}

__device__ __forceinline__ float wave_sum_bc(float x) {
    x = dpp_add<0xB1>(x);   // quad_perm xor1
    x = dpp_add<0x4E>(x);   // quad_perm xor2
    x = dpp_add<0x141>(x);  // row_half_mirror (xor4)
    x = dpp_add<0x140>(x);  // row_mirror (xor8) -> 16-group sums
    x = dpp_add<0x142>(x);  // row_bcast15
    x = dpp_add<0x143>(x);  // row_bcast31
    return __int_as_float(__builtin_amdgcn_readlane(__float_as_int(x), 63));
}

// ---------------- Phase 1: prepend cls, +EPS, L2-normalize, store fp16 packed ----------------
// A: [64 groups][80 rows][1024]  rows 0..36 = img 2g, 37..73 = img 2g+1, 74..79 = 0
// B: [128 caps][64 rows][1024]   row 0 = cls, 1..50 = caps, 51..63 = 0
__global__ __launch_bounds__(256) void norm_kernel(
        const float* __restrict__ img_cls, const float* __restrict__ imgs,
        const float* __restrict__ cap_cls, const float* __restrict__ caps,
        __half* __restrict__ Ah, __half* __restrict__ Bh) {
    __shared__ float red[4];
    const int row = blockIdx.x;
    const int tid = threadIdx.x;

    const float* src = nullptr;
    __half* dst;
    float eps_add = EPSF;
    if (row < 64 * 80) {
        const int g = row / 80, r = row % 80;
        dst = Ah + (size_t)row * 1024;
        int i = -1, rr = 0;
        if (r < 37)      { i = 2 * g;     rr = r; }
        else if (r < 74) { i = 2 * g + 1; rr = r - 37; }
        if (i >= 0) {
            if (rr == 0) { src = img_cls + (size_t)i * 1024; eps_add = 0.0f; }
            else         { src = imgs + ((size_t)i * 36 + (rr - 1)) * 1024; }
        }
    } else {
        const int row2 = row - 64 * 80;
        const int t = row2 >> 6, r = row2 & 63;
        dst = Bh + (size_t)row2 * 1024;
        if (r == 0)       { src = cap_cls + (size_t)t * 1024; eps_add = 0.0f; }
        else if (r <= 50) { src = caps + ((size_t)t * 50 + (r - 1)) * 1024; }
    }

    if (src == nullptr) {  // pad row: zeros (uniform across block)
        ushort4 z; z.x = z.y = z.z = z.w = 0;
        reinterpret_cast<ushort4*>(dst)[tid] = z;
        return;
    }

    float4 v = reinterpret_cast<const float4*>(src)[tid];
    v.x += eps_add; v.y += eps_add; v.z += eps_add; v.w += eps_add;
    float ss = v.x * v.x + v.y * v.y + v.z * v.z + v.w * v.w;
    #pragma unroll
    for (int m = 1; m <= 32; m <<= 1) ss += __shfl_xor(ss, m);
    if ((tid & 63) == 0) red[tid >> 6] = ss;
    __syncthreads();
    const float tot = red[0] + red[1] + red[2] + red[3];
    const float rn = 1.0f / sqrtf(tot);

    ushort4 o;
    o.x = __half_as_ushort(__float2half(v.x * rn));
    o.y = __half_as_ushort(__float2half(v.y * rn));
    o.z = __half_as_ushort(__float2half(v.z * rn));
    o.w = __half_as_ushort(__float2half(v.w * rn));
    reinterpret_cast<ushort4*>(dst)[tid] = o;
}

// ---------------- Phase 2: fused GEMM (BK=32 double-buffer) + Sinkhorn ----------------
// Block: 160 A rows (2 img-groups) x 128 B cols (2 caps), 4 waves.
// Wave (wm, wn) computes 80x64. Staging per K=32 tile: 18 hexadecets (16 rows
// x 64 B each); waves 0,1 take 5, waves 2,3 take 4.
// LDS linear 64B rows; XOR swizzle slot = seg ^ ((row>>1)&3) applied on the
// global source (stage) and on ds_read. For any 8 consecutive lanes the bank
// group 16*(fr&1) + 4*(q4^((fr>>1)&3)) covers all 32 banks -> conflict-free.
__device__ __forceinline__ void stage_oct(const __half* __restrict__ Ag,
                                          const __half* __restrict__ Bg,
                                          __half* buf, int kb, int o, size_t lofs) {
    const __half* src = (o < 10) ? (Ag + (size_t)o * 16384 + kb + lofs)
                                 : (Bg + (size_t)(o - 10) * 16384 + kb + lofs);
    __builtin_amdgcn_global_load_lds((const AS1 void*)src,
                                     (AS3 void*)(buf + o * 512), 16, 0, 0);
}

__device__ __forceinline__ void stage_tile(const __half* __restrict__ Ag,
                                           const __half* __restrict__ Bg,
                                           __half* buf, int kb, int wave,
                                           size_t lofs) {
    stage_oct(Ag, Bg, buf, kb, wave, lofs);
    stage_oct(Ag, Bg, buf, kb, wave + 4, lofs);
    stage_oct(Ag, Bg, buf, kb, wave + 8, lofs);
    stage_oct(Ag, Bg, buf, kb, wave + 12, lofs);
    if (wave < 2) stage_oct(Ag, Bg, buf, kb, wave + 16, lofs);
}

__device__ __forceinline__ void ds_loads32(const __half* buf, int wm, int wn,
                                           int fr, int q4, f16x8 af[5], f16x8 bf[4]) {
    // slot = q4 ^ swz(R); R = base + fr with base % 16 == 0 -> swz = (fr>>1)&3
    const int soff = ((q4 ^ ((fr >> 1) & 3)) * 8);   // swizzled seg, halves
    #pragma unroll
    for (int n = 0; n < 4; ++n) {
        const int R = 160 + wn * 64 + n * 16 + fr;
        bf[n] = *reinterpret_cast<const f16x8*>(buf + R * BK + soff);
    }
    #pragma unroll
    for (int m = 0; m < 5; ++m) {
        const int R = wm * 80 + m * 16 + fr;
        af[m] = *reinterpret_cast<const f16x8*>(buf + R * BK + soff);
    }
}

__device__ __forceinline__ void mfma_cluster(f32x4 acc[5][4], const f16x8 af[5],
                                             const f16x8 bf[4]) {
    __builtin_amdgcn_s_setprio(1);
    #pragma unroll
    for (int m = 0; m < 5; ++m)
        #pragma unroll
        for (int n = 0; n < 4; ++n)
            acc[m][n] = __builtin_amdgcn_mfma_f32_16x16x32_f16(af[m], bf[n], acc[m][n], 0, 0, 0);
    __builtin_amdgcn_s_setprio(0);
}

__global__ __launch_bounds__(256, 4) void fused_kernel(
        const __half* __restrict__ Ah, const __half* __restrict__ Bh,
        const int* __restrict__ img_lens, const int* __restrict__ cap_lens,
        float* __restrict__ out) {
    __shared__ __align__(16) char smem[SMEM_BYTES];   // 37,888 B -> 4 blocks/CU
    __half* lds0 = reinterpret_cast<__half*>(smem);
    __half* lds1 = reinterpret_cast<__half*>(smem + BUF_BYTES);

    // XCD-chunked mapping: 8 consecutive blocks share bx across 8 by slices.
    const int idx = blockIdx.x;            // 0..2047
    const int xcd = idx & 7;
    const int within = idx >> 3;           // 0..255
    const int bx = within >> 3;            // 0..31  (A double-group)
    const int by = xcd * 8 + (within & 7); // 0..63  (cap pair)

    const int tid = threadIdx.x;
    const int wave = tid >> 6;
    const int lane = tid & 63;
    const int wm = wave >> 1, wn = wave & 1;
    const int fr = lane & 15;
    const int q4 = lane >> 4;

    const __half* Ag = Ah + (size_t)bx * 160 * 1024;
    const __half* Bg = Bh + (size_t)by * 2 * 64 * 1024;

    // staging source offset: rsub = lane>>2 (row in hexadecet); stored slot
    // (lane&3) holds global seg (lane&3) ^ ((lane>>3)&3).  LDS dest linear.
    const int rsub = lane >> 2;
    const int segsrc = (lane & 3) ^ ((lane >> 3) & 3);
    const size_t lofs = (size_t)rsub * 1024 + (size_t)(segsrc * 8);

    f32x4 acc[5][4];
    #pragma unroll
    for (int m = 0; m < 5; ++m)
        #pragma unroll
        for (int n = 0; n < 4; ++n) {
            f32x4 z = {0.0f, 0.0f, 0.0f, 0.0f};
            acc[m][n] = z;
        }

    // Prologue: tiles 0 and 1 in flight.
    stage_tile(Ag, Bg, lds0, 0, wave, lofs);
    stage_tile(Ag, Bg, lds1, BK, wave, lofs);
    if (wave < 2) { VM_WAIT(5); } else { VM_WAIT(4); }   // tile 0 landed
    __builtin_amdgcn_s_barrier();

    // Per tile kt (cur = buf[kt&1]):
    //   ds_loads(cur); MFMA (compiler fine-grained lgkmcnt hides read latency
    //   under the cluster); lgkm0 (free) + barrier (ALL waves' reads retired
    //   -> overwrite safe); stage(kt+2 -> cur); vmcnt(own) (kt+1 landed,
    //   kt+2 in flight); barrier
    #pragma unroll 2
    for (int kt = 0; kt < 30; ++kt) {
        __half* cur = (kt & 1) ? lds1 : lds0;
        f16x8 af[5], bf[4];
        ds_loads32(cur, wm, wn, fr, q4, af, bf);
        mfma_cluster(acc, af, bf);
        LGKM0();                          // free: reads already consumed
        __builtin_amdgcn_s_barrier();     // ALL waves' reads of cur retired
        stage_tile(Ag, Bg, cur, (kt + 2) * BK, wave, lofs);
        if (wave < 2) { VM_WAIT(5); } else { VM_WAIT(4); }   // kt+1 landed
        __builtin_amdgcn_s_barrier();
    }
    // ---- tile 30 (no staging; tile 31 in flight) ----
    {
        f16x8 af[5], bf[4];
        ds_loads32(lds0, wm, wn, fr, q4, af, bf);
        mfma_cluster(acc, af, bf);
        VM_WAIT(0);                       // own tile-31 loads landed
        __builtin_amdgcn_s_barrier();     // all waves' tile 31 visible
    }
    // ---- tile 31 ----
    {
        f16x8 af[5], bf[4];
        ds_loads32(lds1, wm, wn, fr, q4, af, bf);
        mfma_cluster(acc, af, bf);
    }

    __syncthreads();   // staging buffers become per-wave fg scratch

    // ---------------- Sinkhorn: wave-private 37x64 f32 fg scratch (9,472 B/wave) ----------------
    // Pass p stores ONLY its 37 valid image rows (predicated):
    //   p=0: wave-local A rows 0..36  -> scratch rows 0..36
    //   p=1: wave-local A rows 37..73 -> scratch rows 0..36
    // Cols XOR-swizzled: col ^ (((srow>>2)&3)<<4). Writes <=2-way (free),
    // reads conflict-free.
    float* fg = reinterpret_cast<float*>(smem) + wave * (37 * 64);
    const int orow = q4 * 4;

    #pragma unroll
    for (int p = 0; p < 2; ++p) {
        if (p) {  // wave-local WAR: pass-0 fg reads must retire before rewrite
            LGKM0();
        }
        #pragma unroll
        for (int pm = 0; pm < 3; ++pm) {
            #pragma unroll
            for (int q = 0; q < 4; ++q) {
                const int lrow = (p ? 32 : 0) + pm * 16 + orow + q;  // wave-local A row
                const int srow = lrow - (p ? 37 : 0);                // scratch row
                const bool ok = p ? (lrow >= 37 && lrow < 74) : (lrow < 37);
                const int sw = ((srow >> 2) & 3) << 4;
                #pragma unroll
                for (int n = 0; n < 4; ++n)
                    if (ok) fg[srow * 64 + ((n * 16 + fr) ^ sw)] = acc[pm + 2 * p][n][q];
            }
        }

        const int i = 4 * bx + 2 * wm + p;
        const int t = 2 * by + wn;
        const int il = img_lens[i] + 1;        // 2..37
        const int cl = cap_lens[t] + 1;        // 2..51
        const bool vcol = lane < cl;

        #define FGR(r_) fg[(r_) * 64 + (lane ^ ((((r_) >> 2) & 3) << 4))]

        float P[37];
        float ts[4] = {0.f, 0.f, 0.f, 0.f};
        #pragma unroll
        for (int r = 0; r < 37; ++r) {
            if (r < il) {                       // wave-uniform branch
                const float f = FGR(r);
                const float pe = vcol ? __expf((f - 1.0f) * 10.0f) : 0.0f;
                P[r] = pe;
                ts[r & 3] += pe;
            } else {
                P[r] = 0.0f;
            }
        }
        float tot = (ts[0] + ts[1]) + (ts[2] + ts[3]);
        tot = wave_sum_bc(tot);
        const float s0 = __builtin_amdgcn_rcpf(tot + EPSF);
        #pragma unroll
        for (int r = 0; r < 37; ++r) P[r] *= s0;

        const float rmarg = 1.0f / (float)il;
        const float cmarg = 1.0f / (float)cl;
        for (int it = 0; it < 3; ++it) {
            #pragma unroll
            for (int r = 0; r < 37; ++r) {
                if (r < il) {
                    const float u = wave_sum_bc(P[r]);
                    P[r] *= rmarg * __builtin_amdgcn_rcpf(u + EPSF);
                }
            }
            float vs[4] = {EPSF, 0.f, 0.f, 0.f};
            #pragma unroll
            for (int r = 0; r < 37; ++r) vs[r & 3] += P[r];
            const float v = (vs[0] + vs[1]) + (vs[2] + vs[3]);
            const float cs = vcol ? cmarg * __builtin_amdgcn_rcpf(v) : 0.0f;
            #pragma unroll
            for (int r = 0; r < 37; ++r) P[r] *= cs;
        }

        float ls[4] = {0.f, 0.f, 0.f, 0.f};
        #pragma unroll
        for (int r = 0; r < 37; ++r) {
            if (r < il) ls[r & 3] += FGR(r) * P[r];   // re-read fg
        }
        float local = (ls[0] + ls[1]) + (ls[2] + ls[3]);
        local = wave_sum_bc(local);
        if (lane == 0) out[i * 128 + t] = local;
        #undef FGR
    }
}

extern "C" void kernel_launch(void* const* d_in, const int* in_sizes, int n_in,
                              void* d_out, int out_size, void* d_ws, size_t ws_size,
                              hipStream_t stream) {
    const float* img_cls  = (const float*)d_in[0];
    const float* imgs     = (const float*)d_in[1];
    const float* cap_cls  = (const float*)d_in[2];
    const float* caps     = (const float*)d_in[3];
    const int*   img_lens = (const int*)d_in[4];
    const int*   cap_lens = (const int*)d_in[5];
    float* out = (float*)d_out;

    __half* Ah = (__half*)d_ws;                          // 64*80*1024 halves = 10.5 MB
    __half* Bh = Ah + (size_t)64 * 80 * 1024;            // 128*64*1024 halves = 16.8 MB

    norm_kernel<<<64 * 80 + 128 * 64, 256, 0, stream>>>(img_cls, imgs, cap_cls, caps, Ah, Bh);
    fused_kernel<<<2048, 256, 0, stream>>>(Ah, Bh, img_lens, cap_lens, out);
}

// Round 5
// 160.767 us; speedup vs baseline: 1.2809x; 1.0464x over previous
//
#include <hip/hip_runtime.h>
#include <hip/hip_fp16.h>

#define EPSF 1e-6f

typedef _Float16 f16x8 __attribute__((ext_vector_type(8)));
typedef float f32x4 __attribute__((ext_vector_type(4)));

#define BK 32                  // K-tile (halves); LDS A row = 64 B (4 x 16B segs)
#define SMEM_BYTES 37888       // fg scratch: 4 waves x 37x64 f32 (staging 2x10240 fits inside)
#define BUF_BYTES 10240        // A staging: 160 rows x 64 B

#define AS1 __attribute__((address_space(1)))
#define AS3 __attribute__((address_space(3)))

#define VM_WAIT(N) asm volatile("s_waitcnt vmcnt(" #N ")" ::: "memory")
#define LGKM0()    asm volatile("s_waitcnt lgkmcnt(0)" ::: "memory")

// ---------- wave sum -> scalar (SGPR) : pure DPP + readlane, no DS ops ----------
template <int CTRL>
__device__ __forceinline__ float dpp_add(float x) {
    int y = __builtin_amdgcn_update_dpp(0, __float_as_int(x), CTRL, 0xf, 0xf, true);
    return x + __int_as_float(y);
}

__device__ __forceinline__ float wave_sum_bc(float x) {
    x = dpp_add<0xB1>(x);   // quad_perm xor1
    x = dpp_add<0x4E>(x);   // quad_perm xor2
    x = dpp_add<0x141>(x);  // row_half_mirror (xor4)
    x = dpp_add<0x140>(x);  // row_mirror (xor8) -> 16-group sums
    x = dpp_add<0x142>(x);  // row_bcast15
    x = dpp_add<0x143>(x);  // row_bcast31
    return __int_as_float(__builtin_amdgcn_readlane(__float_as_int(x), 63));
}

// ---------------- Phase 1: prepend cls, +EPS, L2-normalize, store fp16 ----------------
// A: row-major [64 groups][80 rows][1024]; rows 0..36 = img 2g, 37..73 = img 2g+1.
// B: FRAGMENT-MAJOR: Bh[((t*32 + kt)*4 + n)*512 + lane*8], lane = q4*16+fr.
//    Element (cap t, cap-row r = n*16+fr, K = kt*32 + q4*8 + c) at c within slot.
//    -> fused's load_bf is 4 contiguous 1 KB dwordx4 loads per tile.
__global__ __launch_bounds__(256) void norm_kernel(
        const float* __restrict__ img_cls, const float* __restrict__ imgs,
        const float* __restrict__ cap_cls, const float* __restrict__ caps,
        __half* __restrict__ Ah, __half* __restrict__ Bh) {
    __shared__ float red[4];
    const int row = blockIdx.x;
    const int tid = threadIdx.x;

    const float* src = nullptr;
    __half* dsth;
    float eps_add = EPSF;
    if (row < 64 * 80) {
        const int g = row / 80, r = row % 80;
        dsth = Ah + (size_t)row * 1024 + tid * 4;
        int i = -1, rr = 0;
        if (r < 37)      { i = 2 * g;     rr = r; }
        else if (r < 74) { i = 2 * g + 1; rr = r - 37; }
        if (i >= 0) {
            if (rr == 0) { src = img_cls + (size_t)i * 1024; eps_add = 0.0f; }
            else         { src = imgs + ((size_t)i * 36 + (rr - 1)) * 1024; }
        }
    } else {
        const int row2 = row - 64 * 80;
        const int t = row2 >> 6, r = row2 & 63;
        const int n = r >> 4, fr = r & 15;
        const int kt = tid >> 3, q4 = (tid >> 1) & 3, j = (tid & 1) * 4;
        dsth = Bh + ((size_t)(t * 32 + kt) * 4 + n) * 512 + (q4 * 16 + fr) * 8 + j;
        if (r == 0)       { src = cap_cls + (size_t)t * 1024; eps_add = 0.0f; }
        else if (r <= 50) { src = caps + ((size_t)t * 50 + (r - 1)) * 1024; }
    }

    if (src == nullptr) {  // pad row: zeros (uniform across block)
        ushort4 z; z.x = z.y = z.z = z.w = 0;
        *reinterpret_cast<ushort4*>(dsth) = z;
        return;
    }

    float4 v = reinterpret_cast<const float4*>(src)[tid];
    v.x += eps_add; v.y += eps_add; v.z += eps_add; v.w += eps_add;
    float ss = v.x * v.x + v.y * v.y + v.z * v.z + v.w * v.w;
    #pragma unroll
    for (int m = 1; m <= 32; m <<= 1) ss += __shfl_xor(ss, m);
    if ((tid & 63) == 0) red[tid >> 6] = ss;
    __syncthreads();
    const float tot = red[0] + red[1] + red[2] + red[3];
    const float rn = 1.0f / sqrtf(tot);

    ushort4 o;
    o.x = __half_as_ushort(__float2half(v.x * rn));
    o.y = __half_as_ushort(__float2half(v.y * rn));
    o.z = __half_as_ushort(__float2half(v.z * rn));
    o.w = __half_as_ushort(__float2half(v.w * rn));
    *reinterpret_cast<ushort4*>(dsth) = o;
}

// ---------------- Phase 2: fused GEMM + Sinkhorn ----------------
// Block 160x128, 4 waves; wave (wm,wn) computes 80x64.
// A staged in LDS (2x cross-wave reuse), conflict-free XOR swizzle:
//   slot = q4 ^ ((row>>1)&3); bank group 16*(fr&1)+4*(q4^((fr>>1)&3)) covers
//   all 32 banks for any 8 consecutive lanes.
// B loaded DIRECT global->VGPR from fragment-major Bh (4 coalesced 1KB loads
// per tile), register double-buffered 2 tiles ahead.
// Per-wave VMEM FIFO per tile: +B(kt+2)x4, +A(kt+2)xa; wait vmcnt(4+a)
// -> A(kt+1), B(kt+1) landed; a = 3 (waves 0,1) / 2 (waves 2,3).
__device__ __forceinline__ void stage_octA(const __half* __restrict__ Ag,
                                           __half* buf, int kb, int o, size_t lofs) {
    const __half* src = Ag + (size_t)o * 16384 + kb + lofs;
    __builtin_amdgcn_global_load_lds((const AS1 void*)src,
                                     (AS3 void*)(buf + o * 512), 16, 0, 0);
}

__device__ __forceinline__ void stage_A(const __half* __restrict__ Ag,
                                        __half* buf, int kb, int wave, size_t lofs) {
    stage_octA(Ag, buf, kb, wave, lofs);
    stage_octA(Ag, buf, kb, wave + 4, lofs);
    if (wave < 2) stage_octA(Ag, buf, kb, wave + 8, lofs);
}

__device__ __forceinline__ void ds_af(const __half* buf, int wm, int fr, int q4,
                                      f16x8 af[5]) {
    const int soff = ((q4 ^ ((fr >> 1) & 3)) * 8);   // swizzled seg, halves
    #pragma unroll
    for (int m = 0; m < 5; ++m) {
        const int R = wm * 80 + m * 16 + fr;
        af[m] = *reinterpret_cast<const f16x8*>(buf + R * BK + soff);
    }
}

__device__ __forceinline__ void load_bf(const __half* __restrict__ Bgw, int kt,
                                        f16x8 bf[4]) {
    const __half* p = Bgw + (size_t)kt * 2048;   // Bgw already has +lane*8
    #pragma unroll
    for (int n = 0; n < 4; ++n)
        bf[n] = *reinterpret_cast<const f16x8*>(p + n * 512);
}

__device__ __forceinline__ void mfma_cluster(f32x4 acc[5][4], const f16x8 af[5],
                                             const f16x8 bf[4]) {
    __builtin_amdgcn_s_setprio(1);
    #pragma unroll
    for (int m = 0; m < 5; ++m)
        #pragma unroll
        for (int n = 0; n < 4; ++n)
            acc[m][n] = __builtin_amdgcn_mfma_f32_16x16x32_f16(af[m], bf[n], acc[m][n], 0, 0, 0);
    __builtin_amdgcn_s_setprio(0);
}

__global__ __launch_bounds__(256, 3) void fused_kernel(
        const __half* __restrict__ Ah, const __half* __restrict__ Bh,
        const int* __restrict__ img_lens, const int* __restrict__ cap_lens,
        float* __restrict__ out) {
    __shared__ __align__(16) char smem[SMEM_BYTES];   // 37,888 B
    __half* lds0 = reinterpret_cast<__half*>(smem);
    __half* lds1 = reinterpret_cast<__half*>(smem + BUF_BYTES);

    // XCD-chunked mapping: 8 consecutive blocks share bx across 8 by slices.
    const int idx = blockIdx.x;            // 0..2047
    const int xcd = idx & 7;
    const int within = idx >> 3;           // 0..255
    const int bx = within >> 3;            // 0..31  (A double-group)
    const int by = xcd * 8 + (within & 7); // 0..63  (cap pair)

    const int tid = threadIdx.x;
    const int wave = tid >> 6;
    const int lane = tid & 63;
    const int wm = wave >> 1, wn = wave & 1;
    const int fr = lane & 15;
    const int q4 = lane >> 4;

    const __half* Ag = Ah + (size_t)bx * 160 * 1024;
    const __half* Bgw = Bh + (size_t)(2 * by + wn) * 65536 + lane * 8;

    // A staging source: rsub = lane>>2 (row in hexadecet); stored slot (lane&3)
    // holds global seg (lane&3) ^ ((lane>>3)&3).  LDS dest linear.
    const int rsub = lane >> 2;
    const int segsrc = (lane & 3) ^ ((lane >> 3) & 3);
    const size_t lofs = (size_t)rsub * 1024 + (size_t)(segsrc * 8);

    f32x4 acc[5][4];
    #pragma unroll
    for (int m = 0; m < 5; ++m)
        #pragma unroll
        for (int n = 0; n < 4; ++n) {
            f32x4 z = {0.0f, 0.0f, 0.0f, 0.0f};
            acc[m][n] = z;
        }

    f16x8 bfA[4], bfB[4];

    // Prologue.  FIFO: [B0·4, A0·a, A1·a, B1·4]; wait(4+a) -> B0,A0 done.
    load_bf(Bgw, 0, bfA);
    stage_A(Ag, lds0, 0, wave, lofs);
    stage_A(Ag, lds1, BK, wave, lofs);
    load_bf(Bgw, 1, bfB);
    if (wave < 2) { VM_WAIT(7); } else { VM_WAIT(6); }
    __builtin_amdgcn_s_barrier();

    // Per tile kt (cur LDS = kt&1, CUR regs hold B(kt)):
    //   ds af(cur); MFMA(af, CUR); issue B(kt+2)->CUR; lgkm0+bar (A reads
    //   retired block-wide -> overwrite safe); stage A(kt+2)->cur;
    //   vmcnt(4+a) [A(kt+1), B(kt+1) landed; B(kt+2), A(kt+2) in flight]; bar
    #define GEMM_TILE(KT, LDSBUF, CUR)                                \
    {                                                                 \
        f16x8 af[5];                                                  \
        ds_af((LDSBUF), wm, fr, q4, af);                              \
        mfma_cluster(acc, af, (CUR));                                 \
        load_bf(Bgw, (KT) + 2, (CUR));                                \
        LGKM0();                                                      \
        __builtin_amdgcn_s_barrier();                                 \
        stage_A(Ag, (LDSBUF), ((KT) + 2) * BK, wave, lofs);           \
        if (wave < 2) { VM_WAIT(7); } else { VM_WAIT(6); }            \
        __builtin_amdgcn_s_barrier();                                 \
    }

    #pragma unroll 1
    for (int kt = 0; kt < 30; kt += 2) {
        GEMM_TILE(kt, lds0, bfA);
        GEMM_TILE(kt + 1, lds1, bfB);
    }
    #undef GEMM_TILE

    // ---- tile 30 (no further staging/loads; B31+A31 in flight) ----
    {
        f16x8 af[5];
        ds_af(lds0, wm, fr, q4, af);
        mfma_cluster(acc, af, bfA);      // bfA = B(30), landed at kt=29's wait
        VM_WAIT(0);                      // B31 + own A31 landed
        __builtin_amdgcn_s_barrier();    // A31 visible block-wide
    }
    // ---- tile 31 ----
    {
        f16x8 af[5];
        ds_af(lds1, wm, fr, q4, af);
        mfma_cluster(acc, af, bfB);      // bfB = B(31)
    }

    __syncthreads();   // staging buffers become per-wave fg scratch

    // ---------------- Sinkhorn: wave-private 37x64 f32 fg scratch ----------------
    // Pass p stores only its 37 valid image rows (predicated):
    //   p=0: wave-local A rows 0..36  -> scratch rows 0..36
    //   p=1: wave-local A rows 37..73 -> scratch rows 0..36
    // Cols XOR-swizzled: col ^ (((srow>>2)&3)<<4). Writes <=2-way (free),
    // reads conflict-free.
    float* fg = reinterpret_cast<float*>(smem) + wave * (37 * 64);
    const int orow = q4 * 4;

    #pragma unroll
    for (int p = 0; p < 2; ++p) {
        if (p) {  // wave-local WAR: pass-0 fg reads must retire before rewrite
            LGKM0();
        }
        #pragma unroll
        for (int pm = 0; pm < 3; ++pm) {
            #pragma unroll
            for (int q = 0; q < 4; ++q) {
                const int lrow = (p ? 32 : 0) + pm * 16 + orow + q;  // wave-local A row
                const int srow = lrow - (p ? 37 : 0);                // scratch row
                const bool ok = p ? (lrow >= 37 && lrow < 74) : (lrow < 37);
                const int sw = ((srow >> 2) & 3) << 4;
                #pragma unroll
                for (int n = 0; n < 4; ++n)
                    if (ok) fg[srow * 64 + ((n * 16 + fr) ^ sw)] = acc[pm + 2 * p][n][q];
            }
        }

        const int i = 4 * bx + 2 * wm + p;
        const int t = 2 * by + wn;
        const int il = img_lens[i] + 1;        // 2..37
        const int cl = cap_lens[t] + 1;        // 2..51
        const bool vcol = lane < cl;

        #define FGR(r_) fg[(r_) * 64 + (lane ^ ((((r_) >> 2) & 3) << 4))]

        float P[37];
        float ts[4] = {0.f, 0.f, 0.f, 0.f};
        #pragma unroll
        for (int r = 0; r < 37; ++r) {
            if (r < il) {                       // wave-uniform branch
                const float f = FGR(r);
                const float pe = vcol ? __expf((f - 1.0f) * 10.0f) : 0.0f;
                P[r] = pe;
                ts[r & 3] += pe;
            } else {
                P[r] = 0.0f;
            }
        }
        float tot = (ts[0] + ts[1]) + (ts[2] + ts[3]);
        tot = wave_sum_bc(tot);
        const float s0 = __builtin_amdgcn_rcpf(tot + EPSF);
        #pragma unroll
        for (int r = 0; r < 37; ++r) P[r] *= s0;

        const float rmarg = 1.0f / (float)il;
        const float cmarg = 1.0f / (float)cl;
        for (int it = 0; it < 3; ++it) {
            #pragma unroll
            for (int r = 0; r < 37; ++r) {
                if (r < il) {
                    const float u = wave_sum_bc(P[r]);
                    P[r] *= rmarg * __builtin_amdgcn_rcpf(u + EPSF);
                }
            }
            float vs[4] = {EPSF, 0.f, 0.f, 0.f};
            #pragma unroll
            for (int r = 0; r < 37; ++r) vs[r & 3] += P[r];
            const float v = (vs[0] + vs[1]) + (vs[2] + vs[3]);
            const float cs = vcol ? cmarg * __builtin_amdgcn_rcpf(v) : 0.0f;
            #pragma unroll
            for (int r = 0; r < 37; ++r) P[r] *= cs;
        }

        float ls[4] = {0.f, 0.f, 0.f, 0.f};
        #pragma unroll
        for (int r = 0; r < 37; ++r) {
            if (r < il) ls[r & 3] += FGR(r) * P[r];   // re-read fg
        }
        float local = (ls[0] + ls[1]) + (ls[2] + ls[3]);
        local = wave_sum_bc(local);
        if (lane == 0) out[i * 128 + t] = local;
        #undef FGR
    }
}

extern "C" void kernel_launch(void* const* d_in, const int* in_sizes, int n_in,
                              void* d_out, int out_size, void* d_ws, size_t ws_size,
                              hipStream_t stream) {
    const float* img_cls  = (const float*)d_in[0];
    const float* imgs     = (const float*)d_in[1];
    const float* cap_cls  = (const float*)d_in[2];
    const float* caps     = (const float*)d_in[3];
    const int*   img_lens = (const int*)d_in[4];
    const int*   cap_lens = (const int*)d_in[5];
    float* out = (float*)d_out;

    __half* Ah = (__half*)d_ws;                          // 64*80*1024 halves = 10.5 MB
    __half* Bh = Ah + (size_t)64 * 80 * 1024;            // 128*64*1024 halves = 16.8 MB

    norm_kernel<<<64 * 80 + 128 * 64, 256, 0, stream>>>(img_cls, imgs, cap_cls, caps, Ah, Bh);
    fused_kernel<<<2048, 256, 0, stream>>>(Ah, Bh, img_lens, cap_lens, out);
}

// Round 6
// 159.879 us; speedup vs baseline: 1.2880x; 1.0056x over previous
//
#include <hip/hip_runtime.h>
#include <hip/hip_fp16.h>

#define EPSF 1e-6f

typedef _Float16 f16x8 __attribute__((ext_vector_type(8)));
typedef float f32x4 __attribute__((ext_vector_type(4)));

#define BK 32                  // K-tile (halves); LDS A row = 64 B (4 x 16B segs)
#define SMEM_BYTES 40960       // 4 x 10240 A staging buffers (fg scratch 37,888 fits inside)
#define BUF_BYTES 10240        // A staging: 160 rows x 64 B

#define AS1 __attribute__((address_space(1)))
#define AS3 __attribute__((address_space(3)))

#define VM_WAIT(N) asm volatile("s_waitcnt vmcnt(" #N ")" ::: "memory")
#define LGKM0()    asm volatile("s_waitcnt lgkmcnt(0)" ::: "memory")

// ---------- wave sum -> scalar (SGPR) : pure DPP + readlane, no DS ops ----------
template <int CTRL>
__device__ __forceinline__ float dpp_add(float x) {
    int y = __builtin_amdgcn_update_dpp(0, __float_as_int(x), CTRL, 0xf, 0xf, true);
    return x + __int_as_float(y);
}

__device__ __forceinline__ float wave_sum_bc(float x) {
    x = dpp_add<0xB1>(x);   // quad_perm xor1
    x = dpp_add<0x4E>(x);   // quad_perm xor2
    x = dpp_add<0x141>(x);  // row_half_mirror (xor4)
    x = dpp_add<0x140>(x);  // row_mirror (xor8) -> 16-group sums
    x = dpp_add<0x142>(x);  // row_bcast15
    x = dpp_add<0x143>(x);  // row_bcast31
    return __int_as_float(__builtin_amdgcn_readlane(__float_as_int(x), 63));
}

// ---------------- Phase 1: prepend cls, +EPS, L2-normalize, store fp16 ----------------
// A: row-major [64 groups][80 rows][1024]; rows 0..36 = img 2g, 37..73 = img 2g+1.
// B: FRAGMENT-MAJOR: Bh[((t*32 + kt)*4 + n)*512 + lane*8], lane = q4*16+fr.
//    -> fused's load_bf is 4 contiguous 1 KB dwordx4 loads per tile.
__global__ __launch_bounds__(256) void norm_kernel(
        const float* __restrict__ img_cls, const float* __restrict__ imgs,
        const float* __restrict__ cap_cls, const float* __restrict__ caps,
        __half* __restrict__ Ah, __half* __restrict__ Bh) {
    __shared__ float red[4];
    const int row = blockIdx.x;
    const int tid = threadIdx.x;

    const float* src = nullptr;
    __half* dsth;
    float eps_add = EPSF;
    if (row < 64 * 80) {
        const int g = row / 80, r = row % 80;
        dsth = Ah + (size_t)row * 1024 + tid * 4;
        int i = -1, rr = 0;
        if (r < 37)      { i = 2 * g;     rr = r; }
        else if (r < 74) { i = 2 * g + 1; rr = r - 37; }
        if (i >= 0) {
            if (rr == 0) { src = img_cls + (size_t)i * 1024; eps_add = 0.0f; }
            else         { src = imgs + ((size_t)i * 36 + (rr - 1)) * 1024; }
        }
    } else {
        const int row2 = row - 64 * 80;
        const int t = row2 >> 6, r = row2 & 63;
        const int n = r >> 4, fr = r & 15;
        const int kt = tid >> 3, q4 = (tid >> 1) & 3, j = (tid & 1) * 4;
        dsth = Bh + ((size_t)(t * 32 + kt) * 4 + n) * 512 + (q4 * 16 + fr) * 8 + j;
        if (r == 0)       { src = cap_cls + (size_t)t * 1024; eps_add = 0.0f; }
        else if (r <= 50) { src = caps + ((size_t)t * 50 + (r - 1)) * 1024; }
    }

    if (src == nullptr) {  // pad row: zeros (uniform across block)
        ushort4 z; z.x = z.y = z.z = z.w = 0;
        *reinterpret_cast<ushort4*>(dsth) = z;
        return;
    }

    float4 v = reinterpret_cast<const float4*>(src)[tid];
    v.x += eps_add; v.y += eps_add; v.z += eps_add; v.w += eps_add;
    float ss = v.x * v.x + v.y * v.y + v.z * v.z + v.w * v.w;
    #pragma unroll
    for (int m = 1; m <= 32; m <<= 1) ss += __shfl_xor(ss, m);
    if ((tid & 63) == 0) red[tid >> 6] = ss;
    __syncthreads();
    const float tot = red[0] + red[1] + red[2] + red[3];
    const float rn = 1.0f / sqrtf(tot);

    ushort4 o;
    o.x = __half_as_ushort(__float2half(v.x * rn));
    o.y = __half_as_ushort(__float2half(v.y * rn));
    o.z = __half_as_ushort(__float2half(v.z * rn));
    o.w = __half_as_ushort(__float2half(v.w * rn));
    *reinterpret_cast<ushort4*>(dsth) = o;
}

// ---------------- Phase 2: fused GEMM + Sinkhorn ----------------
// Block 160x128, 4 waves; wave (wm,wn) computes 80x64.
// A staged in LDS, FOUR buffers, staged THREE tiles ahead (2-tile latency
// cover for the L3-resident A panel); conflict-free XOR swizzle.
// B loaded direct global->VGPR from fragment-major Bh, reg double-buffered
// 2 tiles ahead.  ONE barrier per tile:
//   ds_af(buf[kt&3]); MFMA; load B(kt+2); lgkm0; stage A(kt+3)->buf[(kt+3)&3];
//   vmcnt(4+2a)  [A(kt+1),B(kt+1) landed; A(kt+2),B(kt+2),A(kt+3) in flight];
//   barrier      [=> all waves verified tile kt+1 + all reads of the buffer
//                 being overwritten retired (they lgkm0'd pre-prev-barrier)]
// a = 3 (waves 0,1) / 2 (waves 2,3).
__device__ __forceinline__ void stage_octA(const __half* __restrict__ Ag,
                                           __half* buf, int kb, int o, size_t lofs) {
    const __half* src = Ag + (size_t)o * 16384 + kb + lofs;
    __builtin_amdgcn_global_load_lds((const AS1 void*)src,
                                     (AS3 void*)(buf + o * 512), 16, 0, 0);
}

__device__ __forceinline__ void stage_A(const __half* __restrict__ Ag,
                                        __half* buf, int kb, int wave, size_t lofs) {
    stage_octA(Ag, buf, kb, wave, lofs);
    stage_octA(Ag, buf, kb, wave + 4, lofs);
    if (wave < 2) stage_octA(Ag, buf, kb, wave + 8, lofs);
}

__device__ __forceinline__ void ds_af(const __half* buf, int wm, int fr, int q4,
                                      f16x8 af[5]) {
    const int soff = ((q4 ^ ((fr >> 1) & 3)) * 8);   // swizzled seg, halves
    #pragma unroll
    for (int m = 0; m < 5; ++m) {
        const int R = wm * 80 + m * 16 + fr;
        af[m] = *reinterpret_cast<const f16x8*>(buf + R * BK + soff);
    }
}

__device__ __forceinline__ void load_bf(const __half* __restrict__ Bgw, int kt,
                                        f16x8 bf[4]) {
    const __half* p = Bgw + (size_t)kt * 2048;   // Bgw already has +lane*8
    #pragma unroll
    for (int n = 0; n < 4; ++n)
        bf[n] = *reinterpret_cast<const f16x8*>(p + n * 512);
}

__device__ __forceinline__ void mfma_cluster(f32x4 acc[5][4], const f16x8 af[5],
                                             const f16x8 bf[4]) {
    __builtin_amdgcn_s_setprio(1);
    #pragma unroll
    for (int m = 0; m < 5; ++m)
        #pragma unroll
        for (int n = 0; n < 4; ++n)
            acc[m][n] = __builtin_amdgcn_mfma_f32_16x16x32_f16(af[m], bf[n], acc[m][n], 0, 0, 0);
    __builtin_amdgcn_s_setprio(0);
}

__global__ __launch_bounds__(256, 3) void fused_kernel(
        const __half* __restrict__ Ah, const __half* __restrict__ Bh,
        const int* __restrict__ img_lens, const int* __restrict__ cap_lens,
        float* __restrict__ out) {
    __shared__ __align__(16) char smem[SMEM_BYTES];   // 40,960 B -> 3 blocks/CU
    __half* lds0 = reinterpret_cast<__half*>(smem);
    __half* lds1 = reinterpret_cast<__half*>(smem + BUF_BYTES);
    __half* lds2 = reinterpret_cast<__half*>(smem + 2 * BUF_BYTES);
    __half* lds3 = reinterpret_cast<__half*>(smem + 3 * BUF_BYTES);

    // XCD-chunked mapping: 8 consecutive blocks share bx across 8 by slices.
    const int idx = blockIdx.x;            // 0..2047
    const int xcd = idx & 7;
    const int within = idx >> 3;           // 0..255
    const int bx = within >> 3;            // 0..31  (A double-group)
    const int by = xcd * 8 + (within & 7); // 0..63  (cap pair)

    const int tid = threadIdx.x;
    const int wave = tid >> 6;
    const int lane = tid & 63;
    const int wm = wave >> 1, wn = wave & 1;
    const int fr = lane & 15;
    const int q4 = lane >> 4;

    const __half* Ag = Ah + (size_t)bx * 160 * 1024;
    const __half* Bgw = Bh + (size_t)(2 * by + wn) * 65536 + lane * 8;

    // A staging source: rsub = lane>>2 (row in hexadecet); stored slot (lane&3)
    // holds global seg (lane&3) ^ ((lane>>3)&3).  LDS dest linear.
    const int rsub = lane >> 2;
    const int segsrc = (lane & 3) ^ ((lane >> 3) & 3);
    const size_t lofs = (size_t)rsub * 1024 + (size_t)(segsrc * 8);

    f32x4 acc[5][4];
    #pragma unroll
    for (int m = 0; m < 5; ++m)
        #pragma unroll
        for (int n = 0; n < 4; ++n) {
            f32x4 z = {0.0f, 0.0f, 0.0f, 0.0f};
            acc[m][n] = z;
        }

    f16x8 bfA[4], bfB[4];

    // Prologue.  Queue: [A0·a, B0·4, A1·a, B1·4, A2·a]; wait(4+2a) -> A0,B0 done.
    stage_A(Ag, lds0, 0, wave, lofs);
    load_bf(Bgw, 0, bfA);
    stage_A(Ag, lds1, BK, wave, lofs);
    load_bf(Bgw, 1, bfB);
    stage_A(Ag, lds2, 2 * BK, wave, lofs);
    if (wave < 2) { VM_WAIT(10); } else { VM_WAIT(8); }
    __builtin_amdgcn_s_barrier();

    #define GEMM_TILE(KT, RDBUF, STBUF, CUR)                          \
    {                                                                 \
        f16x8 af[5];                                                  \
        ds_af((RDBUF), wm, fr, q4, af);                               \
        mfma_cluster(acc, af, (CUR));                                 \
        load_bf(Bgw, (KT) + 2, (CUR));                                \
        LGKM0();                                                      \
        stage_A(Ag, (STBUF), ((KT) + 3) * BK, wave, lofs);            \
        if (wave < 2) { VM_WAIT(10); } else { VM_WAIT(8); }           \
        __builtin_amdgcn_s_barrier();                                 \
    }

    #pragma unroll 1
    for (int kt = 0; kt < 28; kt += 4) {
        GEMM_TILE(kt,     lds0, lds3, bfA);
        GEMM_TILE(kt + 1, lds1, lds0, bfB);
        GEMM_TILE(kt + 2, lds2, lds1, bfA);
        GEMM_TILE(kt + 3, lds3, lds2, bfB);
    }
    GEMM_TILE(28, lds0, lds3, bfA);   // last full-steady tile (stages A31, loads B30)
    #undef GEMM_TILE

    // ---- tile 29: no staging; load B31 ----
    {
        f16x8 af[5];
        ds_af(lds1, wm, fr, q4, af);
        mfma_cluster(acc, af, bfB);            // B(29)
        load_bf(Bgw, 31, bfB);
        LGKM0();
        // queue: A30·a, B30·4, A31·a, B31·4 ; need A30,B30 -> leave 4+a
        if (wave < 2) { VM_WAIT(7); } else { VM_WAIT(6); }
        __builtin_amdgcn_s_barrier();
    }
    // ---- tile 30 ----
    {
        f16x8 af[5];
        ds_af(lds2, wm, fr, q4, af);
        mfma_cluster(acc, af, bfA);            // B(30), landed at tile-29 wait
        LGKM0();
        VM_WAIT(4);                            // A31 landed; B31 in flight
        __builtin_amdgcn_s_barrier();
    }
    // ---- tile 31 ----
    {
        f16x8 af[5];
        ds_af(lds3, wm, fr, q4, af);
        VM_WAIT(0);                            // B31 landed
        mfma_cluster(acc, af, bfB);
    }

    __syncthreads();   // staging buffers become per-wave fg scratch

    // ---------------- Sinkhorn: wave-private 37x64 f32 fg scratch ----------------
    // Pass p stores only its 37 valid image rows (predicated):
    //   p=0: wave-local A rows 0..36  -> scratch rows 0..36
    //   p=1: wave-local A rows 37..73 -> scratch rows 0..36
    // Cols XOR-swizzled: col ^ (((srow>>2)&3)<<4). Writes <=2-way (free),
    // reads conflict-free.
    float* fg = reinterpret_cast<float*>(smem) + wave * (37 * 64);
    const int orow = q4 * 4;

    #pragma unroll
    for (int p = 0; p < 2; ++p) {
        if (p) {  // wave-local WAR: pass-0 fg reads must retire before rewrite
            LGKM0();
        }
        #pragma unroll
        for (int pm = 0; pm < 3; ++pm) {
            #pragma unroll
            for (int q = 0; q < 4; ++q) {
                const int lrow = (p ? 32 : 0) + pm * 16 + orow + q;  // wave-local A row
                const int srow = lrow - (p ? 37 : 0);                // scratch row
                const bool ok = p ? (lrow >= 37 && lrow < 74) : (lrow < 37);
                const int sw = ((srow >> 2) & 3) << 4;
                #pragma unroll
                for (int n = 0; n < 4; ++n)
                    if (ok) fg[srow * 64 + ((n * 16 + fr) ^ sw)] = acc[pm + 2 * p][n][q];
            }
        }

        const int i = 4 * bx + 2 * wm + p;
        const int t = 2 * by + wn;
        const int il = img_lens[i] + 1;        // 2..37
        const int cl = cap_lens[t] + 1;        // 2..51
        const bool vcol = lane < cl;

        #define FGR(r_) fg[(r_) * 64 + (lane ^ ((((r_) >> 2) & 3) << 4))]

        float P[37];
        float ts[4] = {0.f, 0.f, 0.f, 0.f};
        #pragma unroll
        for (int r = 0; r < 37; ++r) {
            if (r < il) {                       // wave-uniform branch
                const float f = FGR(r);
                const float pe = vcol ? __expf((f - 1.0f) * 10.0f) : 0.0f;
                P[r] = pe;
                ts[r & 3] += pe;
            } else {
                P[r] = 0.0f;
            }
        }
        float tot = (ts[0] + ts[1]) + (ts[2] + ts[3]);
        tot = wave_sum_bc(tot);
        const float s0 = __builtin_amdgcn_rcpf(tot + EPSF);
        #pragma unroll
        for (int r = 0; r < 37; ++r) P[r] *= s0;

        const float rmarg = 1.0f / (float)il;
        const float cmarg = 1.0f / (float)cl;
        for (int it = 0; it < 3; ++it) {
            #pragma unroll
            for (int r = 0; r < 37; ++r) {
                if (r < il) {
                    const float u = wave_sum_bc(P[r]);
                    P[r] *= rmarg * __builtin_amdgcn_rcpf(u + EPSF);
                }
            }
            float vs[4] = {EPSF, 0.f, 0.f, 0.f};
            #pragma unroll
            for (int r = 0; r < 37; ++r) vs[r & 3] += P[r];
            const float v = (vs[0] + vs[1]) + (vs[2] + vs[3]);
            const float cs = vcol ? cmarg * __builtin_amdgcn_rcpf(v) : 0.0f;
            #pragma unroll
            for (int r = 0; r < 37; ++r) P[r] *= cs;
        }

        float ls[4] = {0.f, 0.f, 0.f, 0.f};
        #pragma unroll
        for (int r = 0; r < 37; ++r) {
            if (r < il) ls[r & 3] += FGR(r) * P[r];   // re-read fg
        }
        float local = (ls[0] + ls[1]) + (ls[2] + ls[3]);
        local = wave_sum_bc(local);
        if (lane == 0) out[i * 128 + t] = local;
        #undef FGR
    }
}

extern "C" void kernel_launch(void* const* d_in, const int* in_sizes, int n_in,
                              void* d_out, int out_size, void* d_ws, size_t ws_size,
                              hipStream_t stream) {
    const float* img_cls  = (const float*)d_in[0];
    const float* imgs     = (const float*)d_in[1];
    const float* cap_cls  = (const float*)d_in[2];
    const float* caps     = (const float*)d_in[3];
    const int*   img_lens = (const int*)d_in[4];
    const int*   cap_lens = (const int*)d_in[5];
    float* out = (float*)d_out;

    __half* Ah = (__half*)d_ws;                          // 64*80*1024 halves = 10.5 MB
    __half* Bh = Ah + (size_t)64 * 80 * 1024;            // 128*64*1024 halves = 16.8 MB

    norm_kernel<<<64 * 80 + 128 * 64, 256, 0, stream>>>(img_cls, imgs, cap_cls, caps, Ah, Bh);
    fused_kernel<<<2048, 256, 0, stream>>>(Ah, Bh, img_lens, cap_lens, out);
}

// Round 7
// 150.332 us; speedup vs baseline: 1.3698x; 1.0635x over previous
//
#include <hip/hip_runtime.h>
#include <hip/hip_fp16.h>

#define EPSF 1e-6f

typedef _Float16 f16x8 __attribute__((ext_vector_type(8)));
typedef float f32x4 __attribute__((ext_vector_type(4)));

#define BK 32                  // K-tile (halves); LDS A row = 64 B (4 x 16B segs)
#define SMEM_BYTES 40960       // 4 x 10240 A staging buffers (fg scratch 37,888 fits inside)
#define BUF_BYTES 10240        // A staging: 160 rows x 64 B

#define AS1 __attribute__((address_space(1)))
#define AS3 __attribute__((address_space(3)))

#define VM_WAIT(N) asm volatile("s_waitcnt vmcnt(" #N ")" ::: "memory")
#define LGKM0()    asm volatile("s_waitcnt lgkmcnt(0)" ::: "memory")

// ---------- wave sum -> scalar (SGPR) : pure DPP + readlane, no DS ops ----------
template <int CTRL>
__device__ __forceinline__ float dpp_add(float x) {
    int y = __builtin_amdgcn_update_dpp(0, __float_as_int(x), CTRL, 0xf, 0xf, true);
    return x + __int_as_float(y);
}

__device__ __forceinline__ float wave_sum_bc(float x) {
    x = dpp_add<0xB1>(x);   // quad_perm xor1
    x = dpp_add<0x4E>(x);   // quad_perm xor2
    x = dpp_add<0x141>(x);  // row_half_mirror (xor4)
    x = dpp_add<0x140>(x);  // row_mirror (xor8) -> 16-group sums
    x = dpp_add<0x142>(x);  // row_bcast15
    x = dpp_add<0x143>(x);  // row_bcast31
    return __int_as_float(__builtin_amdgcn_readlane(__float_as_int(x), 63));
}

// ---------------- Phase 1: prepend cls, +EPS, L2-normalize, store fp16 ----------------
// A: row-major [64 groups][80 rows][1024]; rows 0..36 = img 2g, 37..73 = img 2g+1.
// B: FRAGMENT-MAJOR: Bh[((t*32 + kt)*4 + n)*512 + lane*8], lane = q4*16+fr.
//    -> fused's load_bf is 4 contiguous 1 KB dwordx4 loads per tile.
__global__ __launch_bounds__(256) void norm_kernel(
        const float* __restrict__ img_cls, const float* __restrict__ imgs,
        const float* __restrict__ cap_cls, const float* __restrict__ caps,
        __half* __restrict__ Ah, __half* __restrict__ Bh) {
    __shared__ float red[4];
    const int row = blockIdx.x;
    const int tid = threadIdx.x;

    const float* src = nullptr;
    __half* dsth;
    float eps_add = EPSF;
    if (row < 64 * 80) {
        const int g = row / 80, r = row % 80;
        dsth = Ah + (size_t)row * 1024 + tid * 4;
        int i = -1, rr = 0;
        if (r < 37)      { i = 2 * g;     rr = r; }
        else if (r < 74) { i = 2 * g + 1; rr = r - 37; }
        if (i >= 0) {
            if (rr == 0) { src = img_cls + (size_t)i * 1024; eps_add = 0.0f; }
            else         { src = imgs + ((size_t)i * 36 + (rr - 1)) * 1024; }
        }
    } else {
        const int row2 = row - 64 * 80;
        const int t = row2 >> 6, r = row2 & 63;
        const int n = r >> 4, fr = r & 15;
        const int kt = tid >> 3, q4 = (tid >> 1) & 3, j = (tid & 1) * 4;
        dsth = Bh + ((size_t)(t * 32 + kt) * 4 + n) * 512 + (q4 * 16 + fr) * 8 + j;
        if (r == 0)       { src = cap_cls + (size_t)t * 1024; eps_add = 0.0f; }
        else if (r <= 50) { src = caps + ((size_t)t * 50 + (r - 1)) * 1024; }
    }

    if (src == nullptr) {  // pad row: zeros (uniform across block)
        ushort4 z; z.x = z.y = z.z = z.w = 0;
        *reinterpret_cast<ushort4*>(dsth) = z;
        return;
    }

    float4 v = reinterpret_cast<const float4*>(src)[tid];
    v.x += eps_add; v.y += eps_add; v.z += eps_add; v.w += eps_add;
    float ss = v.x * v.x + v.y * v.y + v.z * v.z + v.w * v.w;
    #pragma unroll
    for (int m = 1; m <= 32; m <<= 1) ss += __shfl_xor(ss, m);
    if ((tid & 63) == 0) red[tid >> 6] = ss;
    __syncthreads();
    const float tot = red[0] + red[1] + red[2] + red[3];
    const float rn = 1.0f / sqrtf(tot);

    ushort4 o;
    o.x = __half_as_ushort(__float2half(v.x * rn));
    o.y = __half_as_ushort(__float2half(v.y * rn));
    o.z = __half_as_ushort(__float2half(v.z * rn));
    o.w = __half_as_ushort(__float2half(v.w * rn));
    *reinterpret_cast<ushort4*>(dsth) = o;
}

// ---------------- Phase 2: fused GEMM + Sinkhorn ----------------
// Block 160x128, 4 waves; wave (wm,wn) computes 80x64.
// A staged in LDS, FOUR buffers, staged THREE tiles ahead (2-tile latency
// cover for the L3-resident A panel); conflict-free XOR swizzle.
// B loaded direct global->VGPR from fragment-major Bh, reg double-buffered
// 2 tiles ahead.  ONE barrier per tile. a = 3 (waves 0,1) / 2 (waves 2,3).
__device__ __forceinline__ void stage_octA(const __half* __restrict__ Ag,
                                           __half* buf, int kb, int o, size_t lofs) {
    const __half* src = Ag + (size_t)o * 16384 + kb + lofs;
    __builtin_amdgcn_global_load_lds((const AS1 void*)src,
                                     (AS3 void*)(buf + o * 512), 16, 0, 0);
}

__device__ __forceinline__ void stage_A(const __half* __restrict__ Ag,
                                        __half* buf, int kb, int wave, size_t lofs) {
    stage_octA(Ag, buf, kb, wave, lofs);
    stage_octA(Ag, buf, kb, wave + 4, lofs);
    if (wave < 2) stage_octA(Ag, buf, kb, wave + 8, lofs);
}

__device__ __forceinline__ void ds_af(const __half* buf, int wm, int fr, int q4,
                                      f16x8 af[5]) {
    const int soff = ((q4 ^ ((fr >> 1) & 3)) * 8);   // swizzled seg, halves
    #pragma unroll
    for (int m = 0; m < 5; ++m) {
        const int R = wm * 80 + m * 16 + fr;
        af[m] = *reinterpret_cast<const f16x8*>(buf + R * BK + soff);
    }
}

__device__ __forceinline__ void load_bf(const __half* __restrict__ Bgw, int kt,
                                        f16x8 bf[4]) {
    const __half* p = Bgw + (size_t)kt * 2048;   // Bgw already has +lane*8
    #pragma unroll
    for (int n = 0; n < 4; ++n)
        bf[n] = *reinterpret_cast<const f16x8*>(p + n * 512);
}

__device__ __forceinline__ void mfma_cluster(f32x4 acc[5][4], const f16x8 af[5],
                                             const f16x8 bf[4]) {
    __builtin_amdgcn_s_setprio(1);
    #pragma unroll
    for (int m = 0; m < 5; ++m)
        #pragma unroll
        for (int n = 0; n < 4; ++n)
            acc[m][n] = __builtin_amdgcn_mfma_f32_16x16x32_f16(af[m], bf[n], acc[m][n], 0, 0, 0);
    __builtin_amdgcn_s_setprio(0);
}

__global__ __launch_bounds__(256, 3) void fused_kernel(
        const __half* __restrict__ Ah, const __half* __restrict__ Bh,
        const int* __restrict__ img_lens, const int* __restrict__ cap_lens,
        float* __restrict__ out) {
    __shared__ __align__(16) char smem[SMEM_BYTES];   // 40,960 B -> 3 blocks/CU
    __half* lds0 = reinterpret_cast<__half*>(smem);
    __half* lds1 = reinterpret_cast<__half*>(smem + BUF_BYTES);
    __half* lds2 = reinterpret_cast<__half*>(smem + 2 * BUF_BYTES);
    __half* lds3 = reinterpret_cast<__half*>(smem + 3 * BUF_BYTES);

    // XCD-chunked mapping: 8 consecutive blocks share bx across 8 by slices.
    const int idx = blockIdx.x;            // 0..2047
    const int xcd = idx & 7;
    const int within = idx >> 3;           // 0..255
    const int bx = within >> 3;            // 0..31  (A double-group)
    const int by = xcd * 8 + (within & 7); // 0..63  (cap pair)

    const int tid = threadIdx.x;
    const int wave = tid >> 6;
    const int lane = tid & 63;
    const int wm = wave >> 1, wn = wave & 1;
    const int fr = lane & 15;
    const int q4 = lane >> 4;

    const __half* Ag = Ah + (size_t)bx * 160 * 1024;
    const __half* Bgw = Bh + (size_t)(2 * by + wn) * 65536 + lane * 8;

    // A staging source: rsub = lane>>2 (row in hexadecet); stored slot (lane&3)
    // holds global seg (lane&3) ^ ((lane>>3)&3).  LDS dest linear.
    const int rsub = lane >> 2;
    const int segsrc = (lane & 3) ^ ((lane >> 3) & 3);
    const size_t lofs = (size_t)rsub * 1024 + (size_t)(segsrc * 8);

    f32x4 acc[5][4];
    #pragma unroll
    for (int m = 0; m < 5; ++m)
        #pragma unroll
        for (int n = 0; n < 4; ++n) {
            f32x4 z = {0.0f, 0.0f, 0.0f, 0.0f};
            acc[m][n] = z;
        }

    f16x8 bfA[4], bfB[4];

    // Prologue.  Queue: [A0·a, B0·4, A1·a, B1·4, A2·a]; wait(4+2a) -> A0,B0 done.
    stage_A(Ag, lds0, 0, wave, lofs);
    load_bf(Bgw, 0, bfA);
    stage_A(Ag, lds1, BK, wave, lofs);
    load_bf(Bgw, 1, bfB);
    stage_A(Ag, lds2, 2 * BK, wave, lofs);
    if (wave < 2) { VM_WAIT(10); } else { VM_WAIT(8); }
    __builtin_amdgcn_s_barrier();

    #define GEMM_TILE(KT, RDBUF, STBUF, CUR)                          \
    {                                                                 \
        f16x8 af[5];                                                  \
        ds_af((RDBUF), wm, fr, q4, af);                               \
        mfma_cluster(acc, af, (CUR));                                 \
        load_bf(Bgw, (KT) + 2, (CUR));                                \
        LGKM0();                                                      \
        stage_A(Ag, (STBUF), ((KT) + 3) * BK, wave, lofs);            \
        if (wave < 2) { VM_WAIT(10); } else { VM_WAIT(8); }           \
        __builtin_amdgcn_s_barrier();                                 \
    }

    #pragma unroll 1
    for (int kt = 0; kt < 28; kt += 4) {
        GEMM_TILE(kt,     lds0, lds3, bfA);
        GEMM_TILE(kt + 1, lds1, lds0, bfB);
        GEMM_TILE(kt + 2, lds2, lds1, bfA);
        GEMM_TILE(kt + 3, lds3, lds2, bfB);
    }
    GEMM_TILE(28, lds0, lds3, bfA);   // last full-steady tile (stages A31, loads B30)
    #undef GEMM_TILE

    // ---- tile 29: no staging; load B31 ----
    {
        f16x8 af[5];
        ds_af(lds1, wm, fr, q4, af);
        mfma_cluster(acc, af, bfB);            // B(29)
        load_bf(Bgw, 31, bfB);
        LGKM0();
        // queue: A30·a, B30·4, A31·a, B31·4 ; need A30,B30 -> leave 4+a
        if (wave < 2) { VM_WAIT(7); } else { VM_WAIT(6); }
        __builtin_amdgcn_s_barrier();
    }
    // ---- tile 30 ----
    {
        f16x8 af[5];
        ds_af(lds2, wm, fr, q4, af);
        mfma_cluster(acc, af, bfA);            // B(30), landed at tile-29 wait
        LGKM0();
        VM_WAIT(4);                            // A31 landed; B31 in flight
        __builtin_amdgcn_s_barrier();
    }
    // ---- tile 31 ----
    {
        f16x8 af[5];
        ds_af(lds3, wm, fr, q4, af);
        VM_WAIT(0);                            // B31 landed
        mfma_cluster(acc, af, bfB);
    }

    __syncthreads();   // staging buffers become per-wave fg scratch

    // ---------------- Sinkhorn: wave-private 37x64 f32 fg scratch, BRANCHLESS ----------------
    // Pass p stores only its 37 valid image rows (predicated):
    //   p=0: wave-local A rows 0..36  -> scratch rows 0..36
    //   p=1: wave-local A rows 37..73 -> scratch rows 0..36
    // Cols XOR-swizzled: col ^ (((srow>>2)&3)<<4). Writes <=2-way (free),
    // reads conflict-free.
    // All inner loops are branch-free so the 37 independent DPP reduction
    // chains software-pipeline (the old wave-uniform `if (r<il)` serialized
    // them at chain latency). For r>=il: P[r]==0 exactly -> wave_sum==0 ->
    // P *= rmarg*rcp(EPS) keeps it 0; junk fg reads are killed by cndmask
    // BEFORE any multiply (never 0*inf).
    float* fg = reinterpret_cast<float*>(smem) + wave * (37 * 64);
    const int orow = q4 * 4;

    #pragma unroll
    for (int p = 0; p < 2; ++p) {
        if (p) {  // wave-local WAR: pass-0 fg reads must retire before rewrite
            LGKM0();
        }
        #pragma unroll
        for (int pm = 0; pm < 3; ++pm) {
            #pragma unroll
            for (int q = 0; q < 4; ++q) {
                const int lrow = (p ? 32 : 0) + pm * 16 + orow + q;  // wave-local A row
                const int srow = lrow - (p ? 37 : 0);                // scratch row
                const bool ok = p ? (lrow >= 37 && lrow < 74) : (lrow < 37);
                const int sw = ((srow >> 2) & 3) << 4;
                #pragma unroll
                for (int n = 0; n < 4; ++n)
                    if (ok) fg[srow * 64 + ((n * 16 + fr) ^ sw)] = acc[pm + 2 * p][n][q];
            }
        }

        const int i = 4 * bx + 2 * wm + p;
        const int t = 2 * by + wn;
        const int il = img_lens[i] + 1;        // 2..37
        const int cl = cap_lens[t] + 1;        // 2..51
        const bool vcol = lane < cl;

        #define FGR(r_) fg[(r_) * 64 + (lane ^ ((((r_) >> 2) & 3) << 4))]

        float P[37];
        float ts[4] = {0.f, 0.f, 0.f, 0.f};
        #pragma unroll
        for (int r = 0; r < 37; ++r) {
            const float f = FGR(r);                       // always in-bounds
            const bool act = (r < il) && vcol;
            const float pe = act ? __expf((f - 1.0f) * 10.0f) : 0.0f;  // cndmask kills junk
            P[r] = pe;
            ts[r & 3] += pe;
        }
        float tot = (ts[0] + ts[1]) + (ts[2] + ts[3]);
        tot = wave_sum_bc(tot);
        const float s0 = __builtin_amdgcn_rcpf(tot + EPSF);
        #pragma unroll
        for (int r = 0; r < 37; ++r) P[r] *= s0;

        const float rmarg = 1.0f / (float)il;
        const float cmarg = 1.0f / (float)cl;
        float csave = 0.0f;
        for (int it = 0; it < 3; ++it) {
            #pragma unroll
            for (int r = 0; r < 37; ++r) {                // 37 independent chains
                const float u = wave_sum_bc(P[r]);
                P[r] *= rmarg * __builtin_amdgcn_rcpf(u + EPSF);
            }
            float vs[4] = {EPSF, 0.f, 0.f, 0.f};
            #pragma unroll
            for (int r = 0; r < 37; ++r) vs[r & 3] += P[r];
            const float v = (vs[0] + vs[1]) + (vs[2] + vs[3]);
            const float cs = vcol ? cmarg * __builtin_amdgcn_rcpf(v) : 0.0f;
            if (it < 2) {
                #pragma unroll
                for (int r = 0; r < 37; ++r) P[r] *= cs;
            } else {
                csave = cs;                               // fold last scale into dot
            }
        }

        float ls[4] = {0.f, 0.f, 0.f, 0.f};
        #pragma unroll
        for (int r = 0; r < 37; ++r) {
            const float f = FGR(r);
            const float fm = (r < il) ? f : 0.0f;         // mask BEFORE multiply
            ls[r & 3] = fmaf(fm, P[r], ls[r & 3]);
        }
        float local = csave * ((ls[0] + ls[1]) + (ls[2] + ls[3]));
        local = wave_sum_bc(local);
        if (lane == 0) out[i * 128 + t] = local;
        #undef FGR
    }
}

extern "C" void kernel_launch(void* const* d_in, const int* in_sizes, int n_in,
                              void* d_out, int out_size, void* d_ws, size_t ws_size,
                              hipStream_t stream) {
    const float* img_cls  = (const float*)d_in[0];
    const float* imgs     = (const float*)d_in[1];
    const float* cap_cls  = (const float*)d_in[2];
    const float* caps     = (const float*)d_in[3];
    const int*   img_lens = (const int*)d_in[4];
    const int*   cap_lens = (const int*)d_in[5];
    float* out = (float*)d_out;

    __half* Ah = (__half*)d_ws;                          // 64*80*1024 halves = 10.5 MB
    __half* Bh = Ah + (size_t)64 * 80 * 1024;            // 128*64*1024 halves = 16.8 MB

    norm_kernel<<<64 * 80 + 128 * 64, 256, 0, stream>>>(img_cls, imgs, cap_cls, caps, Ah, Bh);
    fused_kernel<<<2048, 256, 0, stream>>>(Ah, Bh, img_lens, cap_lens, out);
}